// Round 2
// baseline (142.838 us; speedup 1.0000x reference)
//
#include <hip/hip_runtime.h>

// GAT dense attention, fully fused single kernel.
// Softmax numerator factorized rank-1:
//   p_ij = exp(max(z, 0.2z)), z = s_i + t_j  ->  max(alpha_i*E_j, beta_i*F_j)
// Shapes: B=4, N=2048, F_in=128, H=4, d=32. out[b][n][h*32+d] fp32.
//
// Fusion safety: grid = 256 blocks on 256 CUs -> every block is always
// resident (each block fits one CU: 34.8KB LDS, <=256 VGPR via
// __launch_bounds__(512,2)), so the per-bh flag barrier (16 producers per
// group) cannot deadlock. Bounded spin as failsafe (wrong answer, never a
// hang). Magic flags: ws is re-poisoned each iteration; a stale-magic
// replay is a benign race rewriting identical data.

#define LOG2E 1.4426950408889634f
constexpr int Nn = 2048, Fin = 128, Dd = 32;
constexpr unsigned int MAGIC = 0x7A3F19C5u;

typedef _Float16 half8 __attribute__((ext_vector_type(8)));
typedef _Float16 half4v __attribute__((ext_vector_type(4)));
typedef _Float16 half2v __attribute__((ext_vector_type(2)));
typedef float f32x4 __attribute__((ext_vector_type(4)));

union H8 { half2v h2[4]; half8 h8; };

// 256 blocks (16 bh x 16 row-groups of 128) x 512 thr (8 waves).
// Wave w: phase1 = one 16-row M-tile; phase2 = (row-half wr, j-quarter wj).
__global__ __launch_bounds__(512, 2) void k_fused(
    const float* __restrict__ x, const float* __restrict__ W,
    const float* __restrict__ a, _Float16* __restrict__ whT,
    float* __restrict__ tArr, unsigned int* __restrict__ flags,
    float* __restrict__ out) {
  __shared__ float smem[8704];  // 34.8 KB, reused across phases

  int blk = blockIdx.x;
  int bh = blk >> 4, tile = blk & 15;  // 128 rows per block
  int b = bh >> 2, h = bh & 3;
  int tid = threadIdx.x, w = tid >> 6, lane = tid & 63;
  int q = lane >> 4, m = lane & 15;
  int wr = w >> 2, wj = w & 3;

  // phase1 W-stage occupies floats [0,4352); sLoc at 4352 is disjoint, and
  // phase2's Ef/Ff/red stay below float 2560, so sLoc survives until read.
  float* sLoc = smem + 4352;  // [128] own-block s values (phase1 -> phase2)

  int rowbase = tile * 128 + w * 16;

  // ---------------- phase 1: Wh = x @ W (f16 hi/lo 3-MFMA), s, t ----------
  {
    constexpr int KLD = 136;  // halves; mult of 8 -> 16B-aligned b128 reads
    _Float16* BhL = (_Float16*)smem;  // [32][KLD] W hi
    _Float16* BlL = BhL + 32 * KLD;   // [32][KLD] W lo (ends at float 4352)
    const float* Wq = W + h * Fin * Dd;
    {
      // thread: k = tid>>2 (0..127), d = (tid&3)*8 .. +7. Coalesced read,
      // one-time transpose+split into LDS (replaces 64 strided scalar
      // global loads + ~200 cvt VALU per lane in the MFMA loop).
      int k = tid >> 2, dbase = (tid & 3) * 8;
      const float* wp = Wq + k * Dd + dbase;
      float4 w0 = *(const float4*)(wp);
      float4 w1 = *(const float4*)(wp + 4);
      float wv[8] = {w0.x, w0.y, w0.z, w0.w, w1.x, w1.y, w1.z, w1.w};
#pragma unroll
      for (int u = 0; u < 8; ++u) {
        _Float16 hi = (_Float16)wv[u];
        BhL[(dbase + u) * KLD + k] = hi;
        BlL[(dbase + u) * KLD + k] = (_Float16)(wv[u] - (float)hi);
      }
    }
    __syncthreads();

    const float* xb = x + (size_t)(b * Nn + rowbase + m) * Fin;
    f32x4 acc[2];
    acc[0] = (f32x4){0.f, 0.f, 0.f, 0.f};
    acc[1] = (f32x4){0.f, 0.f, 0.f, 0.f};

#pragma unroll
    for (int kt = 0; kt < 4; ++kt) {
      float4 x0 = *(const float4*)(xb + kt * 32 + q * 8);
      float4 x1 = *(const float4*)(xb + kt * 32 + q * 8 + 4);
      float xv[8] = {x0.x, x0.y, x0.z, x0.w, x1.x, x1.y, x1.z, x1.w};
      half8 Ah, Al;
#pragma unroll
      for (int j = 0; j < 8; ++j) {
        _Float16 hi = (_Float16)xv[j];
        Ah[j] = hi;
        Al[j] = (_Float16)(xv[j] - (float)hi);
      }
#pragma unroll
      for (int nt = 0; nt < 2; ++nt) {
        const _Float16* bp = &BhL[(nt * 16 + m) * KLD + kt * 32 + q * 8];
        half8 Bh = *(const half8*)bp;
        half8 Bl = *(const half8*)(bp + 32 * KLD);
        acc[nt] = __builtin_amdgcn_mfma_f32_16x16x32_f16(Ah, Bh, acc[nt], 0, 0, 0);
        acc[nt] = __builtin_amdgcn_mfma_f32_16x16x32_f16(Al, Bh, acc[nt], 0, 0, 0);
        acc[nt] = __builtin_amdgcn_mfma_f32_16x16x32_f16(Ah, Bl, acc[nt], 0, 0, 0);
      }
    }

    // C layout: lane(q,m) -> rows rowbase+q*4+r, col d = nt*16+m.
#pragma unroll
    for (int nt = 0; nt < 2; ++nt) {
      int d = nt * 16 + m;
      half4v h4;
#pragma unroll
      for (int r = 0; r < 4; ++r) h4[r] = (_Float16)acc[nt][r];
      *(half4v*)(whT + (size_t)(bh * Dd + d) * Nn + rowbase + q * 4) = h4;
    }

    const float* ah = a + h * 2 * Dd;
    float a1m0 = ah[m], a1m1 = ah[16 + m];
    float a2m0 = ah[Dd + m], a2m1 = ah[Dd + 16 + m];
#pragma unroll
    for (int r = 0; r < 4; ++r) {
      float ps = acc[0][r] * a1m0 + acc[1][r] * a1m1;
      float pt = acc[0][r] * a2m0 + acc[1][r] * a2m1;
#pragma unroll
      for (int off = 1; off < 16; off <<= 1) {
        ps += __shfl_xor(ps, off);
        pt += __shfl_xor(pt, off);
      }
      if (m == 0) {
        sLoc[w * 16 + q * 4 + r] = ps;              // s stays in LDS
        tArr[bh * Nn + rowbase + q * 4 + r] = pt;   // t needed group-wide
      }
    }
  }

  // ------------- device-scope per-bh barrier (16 blocks/group) -------------
  __threadfence();    // whT/t stores device-visible
  __syncthreads();    // all threads' stores precede the flag
  if (tid == 0)
    __hip_atomic_store(&flags[blk], MAGIC, __ATOMIC_RELEASE,
                       __HIP_MEMORY_SCOPE_AGENT);
  if (tid < 16) {
    int cnt = 0;
    while (__hip_atomic_load(&flags[bh * 16 + tid], __ATOMIC_ACQUIRE,
                             __HIP_MEMORY_SCOPE_AGENT) != MAGIC) {
      __builtin_amdgcn_s_sleep(2);
      if (++cnt > (1 << 21)) break;  // failsafe: never hang the queue
    }
  }
  __syncthreads();
  __threadfence();

  // ---------------- phase 2: h = softmax(e) @ Wh ----------------
  _Float16* Ef = (_Float16*)smem;           // [2048] f16 (floats 0..1023)
  _Float16* Ff = (_Float16*)(smem + 1024);  // [2048] f16 (floats 1024..2047)
  float* red = smem + 2048;                 // [512] block-max scratch

  float tv[4];
  float mx = -1e30f;
#pragma unroll
  for (int k = 0; k < 4; ++k) {
    tv[k] = tArr[bh * Nn + tid + k * 512];
    mx = fmaxf(mx, tv[k]);
  }
  red[tid] = mx;
  __syncthreads();
  for (int ss = 256; ss > 0; ss >>= 1) {
    if (tid < ss) red[tid] = fmaxf(red[tid], red[tid + ss]);
    __syncthreads();
  }
  float T = red[0];
  __syncthreads();
#pragma unroll
  for (int k = 0; k < 4; ++k) {
    float dt = tv[k] - T;  // <= 0
    Ef[tid + k * 512] = (_Float16)__builtin_amdgcn_exp2f(LOG2E * dt);
    Ff[tid + k * 512] = (_Float16)__builtin_amdgcn_exp2f(0.2f * LOG2E * dt);
  }

  // per-row alpha/beta for this wave's 64-row half (replicated f16 pairs)
  half2v aa[4], bb[4];
#pragma unroll
  for (int t = 0; t < 4; ++t) {
    float es = sLoc[wr * 64 + t * 16 + m] + T;
    float al = __builtin_amdgcn_exp2f(0.8f * LOG2E * fminf(es, 0.f));
    float be = __builtin_amdgcn_exp2f(-0.8f * LOG2E * fmaxf(es, 0.f));
    _Float16 ah_ = (_Float16)al, bh_ = (_Float16)be;
    aa[t] = (half2v){ah_, ah_};
    bb[t] = (half2v){bh_, bh_};
  }
  __syncthreads();  // E/F visible to all waves

  f32x4 acc[4][2];
  f32x4 accd[4];
#pragma unroll
  for (int t = 0; t < 4; ++t) {
    acc[t][0] = (f32x4){0.f, 0.f, 0.f, 0.f};
    acc[t][1] = (f32x4){0.f, 0.f, 0.f, 0.f};
    accd[t] = (f32x4){0.f, 0.f, 0.f, 0.f};
  }
  // den via MFMA: B fragment = ones in column 0 (lanes m==0), zero elsewhere.
  // Replaces 64-deep dependent fdot2 chains with independent MFMAs.
  half8 bden;
  {
    _Float16 v = (_Float16)((m == 0) ? 1.f : 0.f);
#pragma unroll
    for (int j = 0; j < 8; ++j) bden[j] = v;
  }

  const _Float16* wb = whT + (size_t)bh * Dd * Nn;

  // main loop: 16 steps of 32 j over this wave's j-quarter; no barriers/exp
  for (int s = 0; s < 16; ++s) {
    int jb = wj * 512 + s * 32;
    half8 B0 = *(const half8*)(wb + (size_t)m * Nn + jb + q * 8);
    half8 B1 = *(const half8*)(wb + (size_t)(16 + m) * Nn + jb + q * 8);
    H8 E, F;
    E.h8 = *(const half8*)&Ef[jb + q * 8];  // LDS b128, quad-broadcast
    F.h8 = *(const half8*)&Ff[jb + q * 8];

#pragma unroll
    for (int t = 0; t < 4; ++t) {
      H8 P;
#pragma unroll
      for (int kk = 0; kk < 4; ++kk) {
        half2v pe = aa[t] * E.h2[kk];                  // v_pk_mul_f16
        half2v pf = bb[t] * F.h2[kk];                  // v_pk_mul_f16
        P.h2[kk] = __builtin_elementwise_max(pe, pf);  // v_pk_max_f16
      }
      acc[t][0] = __builtin_amdgcn_mfma_f32_16x16x32_f16(P.h8, B0, acc[t][0], 0, 0, 0);
      acc[t][1] = __builtin_amdgcn_mfma_f32_16x16x32_f16(P.h8, B1, acc[t][1], 0, 0, 0);
      accd[t]  = __builtin_amdgcn_mfma_f32_16x16x32_f16(P.h8, bden, accd[t], 0, 0, 0);
    }
  }

  // ---- epilogue: cross-wave reduce + divide + elu + store, per row-half ----
  float* redN = smem;         // [4][64][33]
  float* redD = smem + 8448;  // [4][64]
  for (int half = 0; half < 2; ++half) {
    __syncthreads();  // E/F (or previous half's redN) dead
    if (wr == half) {
#pragma unroll
      for (int t = 0; t < 4; ++t) {
#pragma unroll
        for (int dh = 0; dh < 2; ++dh)
#pragma unroll
          for (int r = 0; r < 4; ++r)
            redN[(wj * 64 + t * 16 + q * 4 + r) * 33 + dh * 16 + m] = acc[t][dh][r];
        if (m == 0) {
#pragma unroll
          for (int r = 0; r < 4; ++r)
            redD[wj * 64 + t * 16 + q * 4 + r] = accd[t][r];  // den at col-0
        }
      }
    }
    __syncthreads();
    {
      int rl = tid >> 3, dg = (tid & 7) * 4;  // 64 rows x 8 groups of 4 d
      float num[4];
#pragma unroll
      for (int i = 0; i < 4; ++i)
        num[i] = redN[(0 * 64 + rl) * 33 + dg + i] + redN[(1 * 64 + rl) * 33 + dg + i] +
                 redN[(2 * 64 + rl) * 33 + dg + i] + redN[(3 * 64 + rl) * 33 + dg + i];
      float dt = redD[rl] + redD[64 + rl] + redD[128 + rl] + redD[192 + rl];
      float rd = 1.0f / dt;  // den >= ~1 by construction
      float* orow = out +
          (size_t)(b * Nn + tile * 128 + half * 64 + rl) * (4 * Dd) + h * Dd + dg;
#pragma unroll
      for (int i = 0; i < 4; ++i) {
        float hv = num[i] * rd;
        num[i] = hv > 0.f ? hv : (__builtin_amdgcn_exp2f(hv * LOG2E) - 1.0f);
      }
      *(float4*)orow = make_float4(num[0], num[1], num[2], num[3]);
    }
  }
}

extern "C" void kernel_launch(void* const* d_in, const int* in_sizes, int n_in,
                              void* d_out, int out_size, void* d_ws, size_t ws_size,
                              hipStream_t stream) {
  const float* x = (const float*)d_in[0];   // (4,2048,128)
  const float* W = (const float*)d_in[1];   // (4,128,32)
  const float* a = (const float*)d_in[2];   // (4,64)
  float* out = (float*)d_out;               // (4,2048,128)

  float* wsf = (float*)d_ws;
  float* tArr = wsf;                          // 32768 f32
  _Float16* whT = (_Float16*)(tArr + 32768);  // 16*32*2048 f16 = 2 MB
  unsigned int* flags = (unsigned int*)(whT + 16 * 32 * 2048);  // 256 u32

  k_fused<<<dim3(256), dim3(512), 0, stream>>>(x, W, a, whT, tArr, flags, out);
}

// Round 5
// 76.429 us; speedup vs baseline: 1.8689x; 1.8689x over previous
//
#include <hip/hip_runtime.h>

// GAT dense attention, two kernels (kernel boundary = the inter-phase barrier;
// in-kernel device-scope fences measured catastrophic in round 2: ~85us stall).
// Softmax numerator factorized rank-1:
//   p_ij = exp(max(z, 0.2z)), z = s_i + t_j  ->  max(alpha_i*E_j, beta_i*F_j)
// Shapes: B=4, N=2048, F_in=128, H=4, d=32. out[b][n][h*32+d] fp32.
//
// Round-3 lesson: NEVER assume two __shared__ arrays are adjacent. W-stage
// uses ONE LDS allocation with manual hi/lo offsets (round-2-verified).
// Round-4 was an infra flake (container died pre-run, no diagnostics);
// this source is resubmitted unchanged per theory-first discipline.

#define LOG2E 1.4426950408889634f
constexpr int Nn = 2048, Fin = 128, Dd = 32;

typedef _Float16 half8 __attribute__((ext_vector_type(8)));
typedef _Float16 half4v __attribute__((ext_vector_type(4)));
typedef _Float16 half2v __attribute__((ext_vector_type(2)));
typedef float f32x4 __attribute__((ext_vector_type(4)));

union H8 { half2v h2[4]; half8 h8; };

// ---------------- Kernel 1: Wh = x @ W (f16 hi/lo 3-MFMA), s, t, whT --------
// 512 blocks (16 bh x 32 tiles of 64 rows) x 256 thr; wave = one 16-row M-tile.
// W pre-split hi/lo into one LDS buffer (coalesced, once per block), replacing
// 64 strided scalar global loads + ~200 cvt VALU per lane in the MFMA loop.
__global__ __launch_bounds__(256) void k1_wh(
    const float* __restrict__ x, const float* __restrict__ W,
    const float* __restrict__ a, _Float16* __restrict__ whT,
    float* __restrict__ sArr, float* __restrict__ tArr) {
  constexpr int KLD = 136;  // halves; mult of 8 -> 16B-aligned b128 reads
  __shared__ __align__(16) _Float16 Wlds[2 * 32 * KLD];  // [hi|lo][d][k]
  _Float16* BhL = Wlds;            // explicit offsets within ONE allocation
  _Float16* BlL = Wlds + 32 * KLD;

  int blk = blockIdx.x;
  int bh = blk >> 5, tile = blk & 31;
  int b = bh >> 2, h = bh & 3;
  int tid = threadIdx.x, w = tid >> 6, lane = tid & 63;
  int q = lane >> 4, m = lane & 15;
  int rowbase = tile * 64 + w * 16;

  const float* Wq = W + h * Fin * Dd;
  {
    // thread: k = tid>>1 (0..127), d = (tid&1)*16 .. +15. Fully coalesced.
    int k = tid >> 1, dbase = (tid & 1) * 16;
    const float* wp = Wq + k * Dd + dbase;
    float4 w0 = *(const float4*)(wp);
    float4 w1 = *(const float4*)(wp + 4);
    float4 w2 = *(const float4*)(wp + 8);
    float4 w3 = *(const float4*)(wp + 12);
    float wv[16] = {w0.x, w0.y, w0.z, w0.w, w1.x, w1.y, w1.z, w1.w,
                    w2.x, w2.y, w2.z, w2.w, w3.x, w3.y, w3.z, w3.w};
#pragma unroll
    for (int u = 0; u < 16; ++u) {
      _Float16 hi = (_Float16)wv[u];
      BhL[(dbase + u) * KLD + k] = hi;
      BlL[(dbase + u) * KLD + k] = (_Float16)(wv[u] - (float)hi);
    }
  }
  __syncthreads();

  const float* xb = x + (size_t)(b * Nn + rowbase + m) * Fin;
  f32x4 acc[2];
  acc[0] = (f32x4){0.f, 0.f, 0.f, 0.f};
  acc[1] = (f32x4){0.f, 0.f, 0.f, 0.f};

#pragma unroll
  for (int kt = 0; kt < 4; ++kt) {
    float4 x0 = *(const float4*)(xb + kt * 32 + q * 8);
    float4 x1 = *(const float4*)(xb + kt * 32 + q * 8 + 4);
    float xv[8] = {x0.x, x0.y, x0.z, x0.w, x1.x, x1.y, x1.z, x1.w};
    half8 Ah, Al;
#pragma unroll
    for (int j = 0; j < 8; ++j) {
      _Float16 hi = (_Float16)xv[j];
      Ah[j] = hi;
      Al[j] = (_Float16)(xv[j] - (float)hi);
    }
#pragma unroll
    for (int nt = 0; nt < 2; ++nt) {
      int off = (nt * 16 + m) * KLD + kt * 32 + q * 8;
      half8 Bh = *(const half8*)&BhL[off];
      half8 Bl = *(const half8*)&BlL[off];
      acc[nt] = __builtin_amdgcn_mfma_f32_16x16x32_f16(Ah, Bh, acc[nt], 0, 0, 0);
      acc[nt] = __builtin_amdgcn_mfma_f32_16x16x32_f16(Al, Bh, acc[nt], 0, 0, 0);
      acc[nt] = __builtin_amdgcn_mfma_f32_16x16x32_f16(Ah, Bl, acc[nt], 0, 0, 0);
    }
  }

  // C layout: lane(q,m) -> rows rowbase+q*4+r, col d = nt*16+m.
#pragma unroll
  for (int nt = 0; nt < 2; ++nt) {
    int d = nt * 16 + m;
    half4v h4;
#pragma unroll
    for (int r = 0; r < 4; ++r) h4[r] = (_Float16)acc[nt][r];
    *(half4v*)(whT + (size_t)(bh * Dd + d) * Nn + rowbase + q * 4) = h4;
  }

  const float* ah = a + h * 2 * Dd;
  float a1m0 = ah[m], a1m1 = ah[16 + m];
  float a2m0 = ah[Dd + m], a2m1 = ah[Dd + 16 + m];
#pragma unroll
  for (int r = 0; r < 4; ++r) {
    float ps = acc[0][r] * a1m0 + acc[1][r] * a1m1;
    float pt = acc[0][r] * a2m0 + acc[1][r] * a2m1;
#pragma unroll
    for (int off = 1; off < 16; off <<= 1) {
      ps += __shfl_xor(ps, off);
      pt += __shfl_xor(pt, off);
    }
    if (m == 0) {
      sArr[bh * Nn + rowbase + q * 4 + r] = ps;
      tArr[bh * Nn + rowbase + q * 4 + r] = pt;
    }
  }
}

// ---------------- Kernel 3: h = softmax(e) @ Wh via f16 MFMA ----------------
// Round-0 passing structure: 512 blocks (16 bh x 32 tiles of 64 rows) x 256
// thr = 4 waves (j-quarters). Upgrades (both independently verified):
//   - den via MFMA ones-column B (round-2 phase-2) -> no dependent fdot2 chain
//   - 1-step software prefetch of B0/B1/E/F (same addresses, register rotate)
__global__ __launch_bounds__(256) void k3_attn(
    const _Float16* __restrict__ whT, const float* __restrict__ sArr,
    const float* __restrict__ tArr, float* __restrict__ out) {
  __shared__ float smem[4 * 64 * 33 + 256];  // 34.8 KB union
  _Float16* Ef = (_Float16*)smem;            // [2048] f16 (1024 f32 slots)
  _Float16* Ff = (_Float16*)(smem + 1024);   // [2048] f16
  float* red = smem + 2048;                  // [256] block-max scratch

  int blk = blockIdx.x;
  int bh = blk >> 5, tile = blk & 31;
  int b = bh >> 2, h = bh & 3;
  int tid = threadIdx.x, w = tid >> 6, lane = tid & 63;
  int q = lane >> 4, m = lane & 15;

  // ---- prologue: T, then E_j = 2^(L(t-T)), F_j = 2^(0.2L(t-T)) ----
  float tv[8];
  float mx = -1e30f;
#pragma unroll
  for (int k = 0; k < 8; ++k) {
    tv[k] = tArr[bh * Nn + tid + k * 256];
    mx = fmaxf(mx, tv[k]);
  }
  red[tid] = mx;
  __syncthreads();
  for (int ss = 128; ss > 0; ss >>= 1) {
    if (tid < ss) red[tid] = fmaxf(red[tid], red[tid + ss]);
    __syncthreads();
  }
  float T = red[0];
  __syncthreads();  // red region dead before Ef overwrite (disjoint anyway)
#pragma unroll
  for (int k = 0; k < 8; ++k) {
    float dt = tv[k] - T;  // <= 0
    Ef[tid + k * 256] = (_Float16)__builtin_amdgcn_exp2f(LOG2E * dt);
    Ff[tid + k * 256] = (_Float16)__builtin_amdgcn_exp2f(0.2f * LOG2E * dt);
  }

  // per-row alpha/beta (replicated f16 pairs)
  half2v aa[4], bb[4];
#pragma unroll
  for (int t = 0; t < 4; ++t) {
    float es = sArr[bh * Nn + tile * 64 + t * 16 + m] + T;
    float al = __builtin_amdgcn_exp2f(0.8f * LOG2E * fminf(es, 0.f));
    float be = __builtin_amdgcn_exp2f(-0.8f * LOG2E * fmaxf(es, 0.f));
    _Float16 ah_ = (_Float16)al, bh_ = (_Float16)be;
    aa[t] = (half2v){ah_, ah_};
    bb[t] = (half2v){bh_, bh_};
  }
  __syncthreads();  // E/F visible to all waves

  f32x4 acc[4][2];
  f32x4 accd[4];
#pragma unroll
  for (int t = 0; t < 4; ++t) {
    acc[t][0] = (f32x4){0.f, 0.f, 0.f, 0.f};
    acc[t][1] = (f32x4){0.f, 0.f, 0.f, 0.f};
    accd[t] = (f32x4){0.f, 0.f, 0.f, 0.f};
  }
  // den via MFMA: B fragment = ones in column 0 (lanes m==0), zero elsewhere.
  half8 bden;
  {
    _Float16 v = (_Float16)((m == 0) ? 1.f : 0.f);
#pragma unroll
    for (int j = 0; j < 8; ++j) bden[j] = v;
  }

  const _Float16* wb = whT + (size_t)bh * Dd * Nn;
  const int jb0 = w * 512;

  // ---- main loop: 16 steps of 32 j, 1-step prefetch, no barriers/exp ----
  half8 B0 = *(const half8*)(wb + (size_t)m * Nn + jb0 + q * 8);
  half8 B1 = *(const half8*)(wb + (size_t)(16 + m) * Nn + jb0 + q * 8);
  H8 E, F;
  E.h8 = *(const half8*)&Ef[jb0 + q * 8];
  F.h8 = *(const half8*)&Ff[jb0 + q * 8];

#pragma unroll 2
  for (int s = 0; s < 16; ++s) {
    int jn = jb0 + ((s + 1) & 15) * 32;  // wrap: last iter reloads step 0 (unused)
    half8 nB0 = *(const half8*)(wb + (size_t)m * Nn + jn + q * 8);
    half8 nB1 = *(const half8*)(wb + (size_t)(16 + m) * Nn + jn + q * 8);
    H8 nE, nF;
    nE.h8 = *(const half8*)&Ef[jn + q * 8];
    nF.h8 = *(const half8*)&Ff[jn + q * 8];

#pragma unroll
    for (int t = 0; t < 4; ++t) {
      H8 P;
#pragma unroll
      for (int kk = 0; kk < 4; ++kk) {
        half2v pe = aa[t] * E.h2[kk];                  // v_pk_mul_f16
        half2v pf = bb[t] * F.h2[kk];                  // v_pk_mul_f16
        P.h2[kk] = __builtin_elementwise_max(pe, pf);  // v_pk_max_f16
      }
      acc[t][0] = __builtin_amdgcn_mfma_f32_16x16x32_f16(P.h8, B0, acc[t][0], 0, 0, 0);
      acc[t][1] = __builtin_amdgcn_mfma_f32_16x16x32_f16(P.h8, B1, acc[t][1], 0, 0, 0);
      accd[t]  = __builtin_amdgcn_mfma_f32_16x16x32_f16(P.h8, bden, accd[t], 0, 0, 0);
    }
    B0 = nB0; B1 = nB1; E = nE; F = nF;
  }

  // ---- epilogue: cross-wave reduce + divide + elu + store ----
  __syncthreads();  // E/F dead; reuse smem
  float* redN = smem;                // [4][64][33]
  float* redD = smem + 4 * 64 * 33;  // [4][64]
#pragma unroll
  for (int t = 0; t < 4; ++t) {
#pragma unroll
    for (int dh = 0; dh < 2; ++dh)
#pragma unroll
      for (int r = 0; r < 4; ++r)
        redN[(w * 64 + t * 16 + q * 4 + r) * 33 + dh * 16 + m] = acc[t][dh][r];
    if (m == 0) {
#pragma unroll
      for (int r = 0; r < 4; ++r)
        redD[w * 64 + t * 16 + q * 4 + r] = accd[t][r];  // den at col-0 lanes
    }
  }
  __syncthreads();
  {
    int rl = tid >> 2, dg = (tid & 3) * 8;
    float num[8];
#pragma unroll
    for (int i = 0; i < 8; ++i)
      num[i] = redN[(0 * 64 + rl) * 33 + dg + i] + redN[(1 * 64 + rl) * 33 + dg + i] +
               redN[(2 * 64 + rl) * 33 + dg + i] + redN[(3 * 64 + rl) * 33 + dg + i];
    float dt = redD[rl] + redD[64 + rl] + redD[128 + rl] + redD[192 + rl];
    float rd = 1.0f / dt;  // den >= ~1 by construction
    float* orow = out + (size_t)(b * Nn + tile * 64 + rl) * (4 * Dd) + h * Dd + dg;
#pragma unroll
    for (int i = 0; i < 8; ++i) {
      float hv = num[i] * rd;
      num[i] = hv > 0.f ? hv : (__builtin_amdgcn_exp2f(hv * LOG2E) - 1.0f);
    }
    *(float4*)orow = make_float4(num[0], num[1], num[2], num[3]);
    *((float4*)orow + 1) = make_float4(num[4], num[5], num[6], num[7]);
  }
}

extern "C" void kernel_launch(void* const* d_in, const int* in_sizes, int n_in,
                              void* d_out, int out_size, void* d_ws, size_t ws_size,
                              hipStream_t stream) {
  const float* x = (const float*)d_in[0];   // (4,2048,128)
  const float* W = (const float*)d_in[1];   // (4,128,32)
  const float* a = (const float*)d_in[2];   // (4,64)
  float* out = (float*)d_out;               // (4,2048,128)

  float* wsf = (float*)d_ws;
  float* sArr = wsf;                          // 32768 f32
  float* tArr = sArr + 32768;                 // 32768 f32
  _Float16* whT = (_Float16*)(tArr + 32768);  // 16*32*2048 f16 = 2 MB

  k1_wh<<<dim3(512), dim3(256), 0, stream>>>(x, W, a, whT, sArr, tArr);
  k3_attn<<<dim3(512), dim3(256), 0, stream>>>(whT, sArr, tArr, out);
}